// Round 2
// baseline (393.077 us; speedup 1.0000x reference)
//
#include <hip/hip_runtime.h>

#define EPS_BN 1e-5f
#define HW2 131072u          // float2 elements per channel plane (512*512/2)
#define MSG_OFF 10485760u    // float2 offset of `message` inside d_out (8*10*HW2)

typedef unsigned int u32;
typedef __fp16 h2 __attribute__((ext_vector_type(2)));

union W32 { u32 u; float f; h2 h; };

__device__ __forceinline__ float asf(u32 u){ W32 w; w.u = u; return w.f; }
__device__ __forceinline__ h2    ash(u32 u){ W32 w; w.u = u; return w.h; }
__device__ __forceinline__ u32 packh(float a, float b){
  W32 w; w.h.x = (__fp16)a; w.h.y = (__fp16)b; return w.u;
}

#if __has_builtin(__builtin_amdgcn_fdot2)
__device__ __forceinline__ float dot2(h2 a, h2 b, float c){
  return __builtin_amdgcn_fdot2(a, b, c, false);
}
#else
__device__ __forceinline__ float dot2(h2 a, h2 b, float c){
  return c + (float)a.x * (float)b.x + (float)a.y * (float)b.y;
}
#endif

#if __has_builtin(__builtin_amdgcn_cvt_pkrtz)
__device__ __forceinline__ h2 pk(float a, float b){ return __builtin_amdgcn_cvt_pkrtz(a, b); }
#else
__device__ __forceinline__ h2 pk(float a, float b){ h2 r; r.x = (__fp16)a; r.y = (__fp16)b; return r; }
#endif

// ws (u32 words) layout, BN-folded, f16 K-pair packed weights:
//    0: W1p [10][32] u32   pair cp = channels (2cp,2cp+1) of concat(xh1,xh2)
//  320: B1  [32]  f32
//  352: W2p [16][16] u32   K=32 -> 16 pairs; outputs padded 10->16
//  608: B2  [16]  f32
//  624: W3p [10][32] u32   concat(xf,message)
//  944: B3  [32]  f32
//  976: W4p [16][16] u32
// 1232: B4  [16]  f32
// total 1248 words = 4992 B

extern "C" __global__ void prep_kernel(
  const float* __restrict__ w1, const float* __restrict__ g1, const float* __restrict__ b1, const float* __restrict__ m1, const float* __restrict__ v1,
  const float* __restrict__ w2, const float* __restrict__ g2, const float* __restrict__ b2, const float* __restrict__ m2, const float* __restrict__ v2,
  const float* __restrict__ w3, const float* __restrict__ g3, const float* __restrict__ b3, const float* __restrict__ m3, const float* __restrict__ v3,
  const float* __restrict__ w4, const float* __restrict__ g4, const float* __restrict__ b4, const float* __restrict__ m4, const float* __restrict__ v4,
  u32* __restrict__ ws)
{
  const int t = threadIdx.x;
  // W1p [10][32]: w1 is [32][20]
  for (int i = t; i < 320; i += 256){ int cp = i >> 5, o = i & 31;
    float sc = g1[o] * rsqrtf(v1[o] + EPS_BN);
    ws[i] = packh(w1[o*20 + 2*cp] * sc, w1[o*20 + 2*cp + 1] * sc); }
  for (int i = t; i < 32; i += 256){
    float sc = g1[i] * rsqrtf(v1[i] + EPS_BN);
    W32 w; w.f = b1[i] - m1[i] * sc; ws[320 + i] = w.u; }
  // W2p [16][16]: w2 is [10][32]
  for (int i = t; i < 256; i += 256){ int cp = i >> 4, o = i & 15; u32 val = 0u;
    if (o < 10){ float sc = g2[o] * rsqrtf(v2[o] + EPS_BN);
      val = packh(w2[o*32 + 2*cp] * sc, w2[o*32 + 2*cp + 1] * sc); }
    ws[352 + i] = val; }
  for (int i = t; i < 16; i += 256){ W32 w; w.f = 0.f;
    if (i < 10){ float sc = g2[i] * rsqrtf(v2[i] + EPS_BN); w.f = b2[i] - m2[i] * sc; }
    ws[608 + i] = w.u; }
  // W3p [10][32]: w3 is [32][20]
  for (int i = t; i < 320; i += 256){ int cp = i >> 5, o = i & 31;
    float sc = g3[o] * rsqrtf(v3[o] + EPS_BN);
    ws[624 + i] = packh(w3[o*20 + 2*cp] * sc, w3[o*20 + 2*cp + 1] * sc); }
  for (int i = t; i < 32; i += 256){
    float sc = g3[i] * rsqrtf(v3[i] + EPS_BN);
    W32 w; w.f = b3[i] - m3[i] * sc; ws[944 + i] = w.u; }
  // W4p [16][16]: w4 is [10][32]
  for (int i = t; i < 256; i += 256){ int cp = i >> 4, o = i & 15; u32 val = 0u;
    if (o < 10){ float sc = g4[o] * rsqrtf(v4[o] + EPS_BN);
      val = packh(w4[o*32 + 2*cp] * sc, w4[o*32 + 2*cp + 1] * sc); }
    ws[976 + i] = val; }
  for (int i = t; i < 16; i += 256){ W32 w; w.f = 0.f;
    if (i < 10){ float sc = g4[i] * rsqrtf(v4[i] + EPS_BN); w.f = b4[i] - m4[i] * sc; }
    ws[1232 + i] = w.u; }
}

// 4 outputs from one uint4 of f16-pair weights, for both pixels (x,y)
#define DO4(AX, AY, HX, HY, Q, O0) \
  { h2 w0_ = ash((Q).x), w1_ = ash((Q).y), w2_ = ash((Q).z), w3_ = ash((Q).w); \
    AX[(O0)+0] = dot2(HX, w0_, AX[(O0)+0]); AY[(O0)+0] = dot2(HY, w0_, AY[(O0)+0]); \
    AX[(O0)+1] = dot2(HX, w1_, AX[(O0)+1]); AY[(O0)+1] = dot2(HY, w1_, AY[(O0)+1]); \
    AX[(O0)+2] = dot2(HX, w2_, AX[(O0)+2]); AY[(O0)+2] = dot2(HY, w2_, AY[(O0)+2]); \
    AX[(O0)+3] = dot2(HX, w3_, AX[(O0)+3]); AY[(O0)+3] = dot2(HY, w3_, AY[(O0)+3]); }

// init variant: acc starts at bias -- folds the bias-init v_movs into the first dot
#define DO4i(AX, AY, HX, HY, Q, O0, BB) \
  { h2 w0_ = ash((Q).x), w1_ = ash((Q).y), w2_ = ash((Q).z), w3_ = ash((Q).w); \
    float b0_ = asf(s[(BB)+(O0)+0]), b1_ = asf(s[(BB)+(O0)+1]); \
    float b2_ = asf(s[(BB)+(O0)+2]), b3_ = asf(s[(BB)+(O0)+3]); \
    AX[(O0)+0] = dot2(HX, w0_, b0_); AY[(O0)+0] = dot2(HY, w0_, b0_); \
    AX[(O0)+1] = dot2(HX, w1_, b1_); AY[(O0)+1] = dot2(HY, w1_, b1_); \
    AX[(O0)+2] = dot2(HX, w2_, b2_); AY[(O0)+2] = dot2(HY, w2_, b2_); \
    AX[(O0)+3] = dot2(HX, w3_, b3_); AY[(O0)+3] = dot2(HY, w3_, b3_); }

// Fully fused per-pixel MLP, f32 in / f32 out, f16-dot2 internal math.
// Each thread handles 2 pixels (float2 per channel-plane load, coalesced).
// Weights are read DIRECTLY from global via wave-uniform constant-offset
// addresses -> compiler scalarizes to s_load / SGPRs (K$-resident, 5 KB).
// No LDS, no __syncthreads: frees the LDS pipe (was ~256 ds_read_b128/wave).
extern "C" __global__ __launch_bounds__(256) void fused_kernel(
  const float2* __restrict__ xf, const float2* __restrict__ xh1, const float2* __restrict__ xh2,
  const u32* __restrict__ wsp, float2* __restrict__ out)
{
  const u32* __restrict__ s = wsp;   // uniform base; all indices compile-time

  const unsigned p  = blockIdx.x * 256u + threadIdx.x;  // pixel-pair index
  const unsigned b  = p >> 17;
  const unsigned hw = p & (HW2 - 1u);
  const size_t base = (size_t)b * (10u * HW2) + hw;
  const float2* A1 = xh1 + base;
  const float2* A2 = xh2 + base;
  const float2* AF = xf  + base;

  float ax[32], ay[32];
  h2 px[10], py[10];

  // ---- block 1 inputs: concat(xh1, xh2), 20 channels -> 10 pairs ----
  #pragma unroll
  for (int cp = 0; cp < 5; cp++){
    float2 c0 = A1[(size_t)(2*cp) * HW2];
    float2 c1 = A1[(size_t)(2*cp + 1) * HW2];
    px[cp] = pk(c0.x, c1.x); py[cp] = pk(c0.y, c1.y);
  }
  #pragma unroll
  for (int cp = 0; cp < 5; cp++){
    float2 c0 = A2[(size_t)(2*cp) * HW2];
    float2 c1 = A2[(size_t)(2*cp + 1) * HW2];
    px[5+cp] = pk(c0.x, c1.x); py[5+cp] = pk(c0.y, c1.y);
  }

  // ---- block 1, conv1: 20 -> 32 (cp=0 peeled: bias folded into first dot) ----
  { const uint4* wr = (const uint4*)&s[0];
    h2 hx = px[0], hy = py[0];
    #pragma unroll
    for (int j = 0; j < 8; j++){ uint4 q = wr[j]; DO4i(ax, ay, hx, hy, q, 4*j, 320); } }
  #pragma unroll
  for (int cp = 1; cp < 10; cp++){
    const uint4* wr = (const uint4*)&s[cp * 32];
    h2 hx = px[cp], hy = py[cp];
    #pragma unroll
    for (int j = 0; j < 8; j++){ uint4 q = wr[j]; DO4(ax, ay, hx, hy, q, 4*j); }
  }
  #pragma unroll
  for (int o = 0; o < 32; o++){ ax[o] = fmaxf(ax[o], 0.f); ay[o] = fmaxf(ay[o], 0.f); }

  // ---- hoist xf loads: HBM latency hides under block-1 conv2 ----
  #pragma unroll
  for (int cp = 0; cp < 5; cp++){
    float2 c0 = AF[(size_t)(2*cp) * HW2];
    float2 c1 = AF[(size_t)(2*cp + 1) * HW2];
    px[cp] = pk(c0.x, c1.x); py[cp] = pk(c0.y, c1.y);
  }

  // ---- block 1, conv2: 32 -> 10 (message) ----
  float mx[10], my[10];
  h2 qx[16], qy[16];
  #pragma unroll
  for (int k = 0; k < 16; k++){ qx[k] = pk(ax[2*k], ax[2*k+1]); qy[k] = pk(ay[2*k], ay[2*k+1]); }
  { const uint4* wr = (const uint4*)&s[352];
    h2 hx = qx[0], hy = qy[0];
    uint4 q0 = wr[0]; DO4i(mx, my, hx, hy, q0, 0, 608);
    uint4 q1 = wr[1]; DO4i(mx, my, hx, hy, q1, 4, 608);
    uint4 q2 = wr[2];
    { h2 w0_ = ash(q2.x), w1_ = ash(q2.y);
      float b8_ = asf(s[608+8]), b9_ = asf(s[608+9]);
      mx[8] = dot2(hx, w0_, b8_); my[8] = dot2(hy, w0_, b8_);
      mx[9] = dot2(hx, w1_, b9_); my[9] = dot2(hy, w1_, b9_); } }
  #pragma unroll
  for (int cp = 1; cp < 16; cp++){
    const uint4* wr = (const uint4*)&s[352 + cp * 16];
    h2 hx = qx[cp], hy = qy[cp];
    uint4 q0 = wr[0]; DO4(mx, my, hx, hy, q0, 0);
    uint4 q1 = wr[1]; DO4(mx, my, hx, hy, q1, 4);
    uint4 q2 = wr[2];
    { h2 w0_ = ash(q2.x), w1_ = ash(q2.y);
      mx[8] = dot2(hx, w0_, mx[8]); my[8] = dot2(hy, w0_, my[8]);
      mx[9] = dot2(hx, w1_, mx[9]); my[9] = dot2(hy, w1_, my[9]); }
  }
  #pragma unroll
  for (int o = 0; o < 10; o++){ mx[o] = fmaxf(mx[o], 0.f); my[o] = fmaxf(my[o], 0.f); }
  #pragma unroll
  for (int o = 0; o < 10; o++){
    float2 r; r.x = mx[o]; r.y = my[o];
    out[MSG_OFF + base + (size_t)o * HW2] = r;
  }

  // ---- block 2, conv1: [xf;message](20) -> 32 ----
  #pragma unroll
  for (int k = 0; k < 5; k++){
    px[5+k] = pk(mx[2*k], mx[2*k+1]); py[5+k] = pk(my[2*k], my[2*k+1]);
  }
  { const uint4* wr = (const uint4*)&s[624];
    h2 hx = px[0], hy = py[0];
    #pragma unroll
    for (int j = 0; j < 8; j++){ uint4 q = wr[j]; DO4i(ax, ay, hx, hy, q, 4*j, 944); } }
  #pragma unroll
  for (int cp = 1; cp < 10; cp++){
    const uint4* wr = (const uint4*)&s[624 + cp * 32];
    h2 hx = px[cp], hy = py[cp];
    #pragma unroll
    for (int j = 0; j < 8; j++){ uint4 q = wr[j]; DO4(ax, ay, hx, hy, q, 4*j); }
  }
  #pragma unroll
  for (int o = 0; o < 32; o++){ ax[o] = fmaxf(ax[o], 0.f); ay[o] = fmaxf(ay[o], 0.f); }

  // ---- block 2, conv2: 32 -> 10 (xf_new) ----
  float ox[10], oy[10];
  #pragma unroll
  for (int k = 0; k < 16; k++){ qx[k] = pk(ax[2*k], ax[2*k+1]); qy[k] = pk(ay[2*k], ay[2*k+1]); }
  { const uint4* wr = (const uint4*)&s[976];
    h2 hx = qx[0], hy = qy[0];
    uint4 q0 = wr[0]; DO4i(ox, oy, hx, hy, q0, 0, 1232);
    uint4 q1 = wr[1]; DO4i(ox, oy, hx, hy, q1, 4, 1232);
    uint4 q2 = wr[2];
    { h2 w0_ = ash(q2.x), w1_ = ash(q2.y);
      float b8_ = asf(s[1232+8]), b9_ = asf(s[1232+9]);
      ox[8] = dot2(hx, w0_, b8_); oy[8] = dot2(hy, w0_, b8_);
      ox[9] = dot2(hx, w1_, b9_); oy[9] = dot2(hy, w1_, b9_); } }
  #pragma unroll
  for (int cp = 1; cp < 16; cp++){
    const uint4* wr = (const uint4*)&s[976 + cp * 16];
    h2 hx = qx[cp], hy = qy[cp];
    uint4 q0 = wr[0]; DO4(ox, oy, hx, hy, q0, 0);
    uint4 q1 = wr[1]; DO4(ox, oy, hx, hy, q1, 4);
    uint4 q2 = wr[2];
    { h2 w0_ = ash(q2.x), w1_ = ash(q2.y);
      ox[8] = dot2(hx, w0_, ox[8]); oy[8] = dot2(hy, w0_, oy[8]);
      ox[9] = dot2(hx, w1_, ox[9]); oy[9] = dot2(hy, w1_, oy[9]); }
  }
  #pragma unroll
  for (int o = 0; o < 10; o++){
    float2 r; r.x = fmaxf(ox[o], 0.f); r.y = fmaxf(oy[o], 0.f);
    out[base + (size_t)o * HW2] = r;
  }
}

extern "C" void kernel_launch(void* const* d_in, const int* in_sizes, int n_in,
                              void* d_out, int out_size, void* d_ws, size_t ws_size,
                              hipStream_t stream)
{
  u32* ws = (u32*)d_ws;
  prep_kernel<<<1, 256, 0, stream>>>(
    (const float*)d_in[3],  (const float*)d_in[4],  (const float*)d_in[5],  (const float*)d_in[6],  (const float*)d_in[7],
    (const float*)d_in[8],  (const float*)d_in[9],  (const float*)d_in[10], (const float*)d_in[11], (const float*)d_in[12],
    (const float*)d_in[13], (const float*)d_in[14], (const float*)d_in[15], (const float*)d_in[16], (const float*)d_in[17],
    (const float*)d_in[18], (const float*)d_in[19], (const float*)d_in[20], (const float*)d_in[21], (const float*)d_in[22],
    ws);

  // 8*512*512 pixels / 2 per thread = 1,048,576 threads = 4096 blocks x 256
  fused_kernel<<<4096, 256, 0, stream>>>(
    (const float2*)d_in[0], (const float2*)d_in[1], (const float2*)d_in[2],
    ws, (float2*)d_out);
}